// Round 15
// baseline (488.466 us; speedup 1.0000x reference)
//
#include <hip/hip_runtime.h>

#define D 128
#define NB_E 512  // edge-slice blocks for bucket count/scatter
// Panel layout: 16 panels x 8 cols (16B per node-row), panel p holds
// cols [p*8, p*8+8) for all nodes, contiguous: buf[(p*n_nodes + node)*8].
// Panel pair (2q, 2q+1) pinned to XCD q via blockIdx&7 -> 3.2MB < 4MB L2.

typedef __attribute__((ext_vector_type(8))) short bf16x8;
typedef __attribute__((ext_vector_type(16))) float f32x16;

__device__ inline float b2f(unsigned int hi16_as_lo) {
  union { unsigned int u; float f; } v;
  v.u = hi16_as_lo;
  return v.f;
}
__device__ inline unsigned short f2b(float f) {  // RNE f32 -> bf16
  union { float f; unsigned int u; } v;
  v.f = f;
  unsigned int r = v.u + 0x7FFFu + ((v.u >> 16) & 1u);
  return (unsigned short)(r >> 16);
}
__device__ inline unsigned int pk2(float lo, float hi) {
  return (unsigned int)f2b(lo) | ((unsigned int)f2b(hi) << 16);
}
__device__ inline int lbound(const int* __restrict__ a, int n, int key) {
  int lo = 0, hi = n;
  while (lo < hi) {
    int mid = (lo + hi) >> 1;
    if (a[mid] < key) lo = mid + 1; else hi = mid;
  }
  return lo;
}

// ---------------------------------------------------------------------------
// prep: fused {bktA histogram | weight pack x6 | f32 -> bf16 panel convert}
// blocks [0,NB_E): bktA; [NB_E,NB_E+48): pack; rest: convert (128 nodes/blk,
// LDS transpose row-major f32 -> 16 panels of 8 bf16 cols).
// ---------------------------------------------------------------------------
__global__ __launch_bounds__(256) void prep_kernel(
    const float* __restrict__ x, unsigned short* __restrict__ xp,
    const float* __restrict__ w0, const float* __restrict__ w1,
    const float* __restrict__ w2, const float* __restrict__ w3,
    const float* __restrict__ w4, const float* __restrict__ w5,
    unsigned short* __restrict__ Wp, const int* __restrict__ dst,
    int* __restrict__ bcount, int n_nodes, int n_edges, int NBU, int epb) {
  __shared__ char smem[128 * 136 * 2];  // 34816 B
  const int b = blockIdx.x;
  if (b < NB_E) {  // ---- bktA ----
    int* cnt = (int*)smem;
    for (int i = threadIdx.x; i < NBU; i += 256) cnt[i] = 0;
    __syncthreads();
    const int e0 = b * epb;
    const int e1 = min(e0 + epb, n_edges);
    for (int e = e0 + threadIdx.x; e < e1; e += 256)
      atomicAdd(&cnt[dst[e] >> 8], 1);
    __syncthreads();
    int* out = bcount + (size_t)b * NBU;
    for (int i = threadIdx.x; i < NBU; i += 256) out[i] = cnt[i];
  } else if (b < NB_E + 48) {  // ---- pack ----
    const int bb = b - NB_E;
    const int m = bb >> 3;
    const float* W = m == 0 ? w0
                   : m == 1 ? w1
                   : m == 2 ? w2
                   : m == 3 ? w3
                   : m == 4 ? w4
                            : w5;
    const int idx = (bb & 7) * 256 + threadIdx.x;  // 0..2047
    const int l = idx & 63;
    const int s = (idx >> 6) & 7;
    const int t = idx >> 9;
    const int n = (t << 5) + (l & 31);
    const int k0 = (s << 4) + ((l >> 5) << 3);
    unsigned short o[8];
#pragma unroll
    for (int i = 0; i < 8; ++i) o[i] = f2b(W[(size_t)(k0 + i) * D + n]);
    *reinterpret_cast<bf16x8*>(Wp + (size_t)m * 16384 + (size_t)idx * 8) =
        *reinterpret_cast<bf16x8*>(o);
  } else {  // ---- convert to panels ----
    unsigned short* lds = (unsigned short*)smem;  // [128][136]
    const int cb = b - NB_E - 48;
    const int node0 = cb * 128;
    for (int f = threadIdx.x; f < 4096; f += 256) {
      const int nd = f >> 5;   // node within block
      const int c4 = f & 31;   // float4 index within row
      if (node0 + nd < n_nodes) {
        const float4 v = *reinterpret_cast<const float4*>(
            x + (size_t)(node0 + nd) * D + c4 * 4);
        unsigned short* dstp = lds + nd * 136 + c4 * 4;
        dstp[0] = f2b(v.x);
        dstp[1] = f2b(v.y);
        dstp[2] = f2b(v.z);
        dstp[3] = f2b(v.w);
      }
    }
    __syncthreads();
    for (int c = threadIdx.x; c < 2048; c += 256) {
      const int p = c >> 7;
      const int nd = c & 127;
      if (node0 + nd < n_nodes) {
        const bf16x8 v = *reinterpret_cast<const bf16x8*>(lds + nd * 136 + p * 8);
        *reinterpret_cast<bf16x8*>(xp + ((size_t)p * n_nodes + node0 + nd) * 8) = v;
      }
    }
  }
}

// ---------------------------------------------------------------------------
// bktB: per bucket j, exclusive scan of bcount[b][j] over blocks b.
// ---------------------------------------------------------------------------
__global__ __launch_bounds__(256) void bktB_kernel(
    const int* __restrict__ bcount, int* __restrict__ boff,
    int* __restrict__ btot, int NBU) {
  __shared__ int lds[256];
  const int j = blockIdx.x;
  const int t = threadIdx.x;
  const int a = bcount[(size_t)(2 * t) * NBU + j];
  const int b = bcount[(size_t)(2 * t + 1) * NBU + j];
  const int s = a + b;
  lds[t] = s;
  __syncthreads();
#pragma unroll
  for (int off = 1; off < 256; off <<= 1) {
    int p = 0;
    if (t >= off) p = lds[t - off];
    __syncthreads();
    lds[t] += p;
    __syncthreads();
  }
  const int excl = lds[t] - s;
  boff[(size_t)(2 * t) * NBU + j] = excl;
  boff[(size_t)(2 * t + 1) * NBU + j] = excl + a;
  if (t == 255) btot[j] = lds[255];
}

// ---------------------------------------------------------------------------
// bktC: scatter edges into bucket-grouped ebuf ((dstLocal<<17)|src).
// ---------------------------------------------------------------------------
__global__ __launch_bounds__(256) void bktC_kernel(
    const int* __restrict__ src, const int* __restrict__ dst,
    const int* __restrict__ boff, const int* __restrict__ btot,
    unsigned int* __restrict__ ebuf, int n_edges, int NBU, int epb) {
  __shared__ int cur[512];
  __shared__ int scan[256];
  const int t = threadIdx.x;
  const int a = (2 * t < NBU) ? btot[2 * t] : 0;
  const int b = (2 * t + 1 < NBU) ? btot[2 * t + 1] : 0;
  const int s = a + b;
  scan[t] = s;
  __syncthreads();
#pragma unroll
  for (int off = 1; off < 256; off <<= 1) {
    int p = 0;
    if (t >= off) p = scan[t - off];
    __syncthreads();
    scan[t] += p;
    __syncthreads();
  }
  const int excl = scan[t] - s;
  const int* bo = boff + (size_t)blockIdx.x * NBU;
  if (2 * t < NBU) cur[2 * t] = excl + bo[2 * t];
  if (2 * t + 1 < NBU) cur[2 * t + 1] = excl + a + bo[2 * t + 1];
  __syncthreads();
  const int e0 = blockIdx.x * epb;
  const int e1 = min(e0 + epb, n_edges);
  for (int e = e0 + t; e < e1; e += 256) {
    const int d = dst[e];
    const int pos = atomicAdd(&cur[d >> 8], 1);
    ebuf[pos] = ((unsigned int)(d & 255) << 17) | (unsigned int)src[e];
  }
}

// ---------------------------------------------------------------------------
// bktD: per bucket, LDS hist -> scan -> rowptr + LDS-cursor fill of col.
// ---------------------------------------------------------------------------
__global__ __launch_bounds__(256) void bktD_kernel(
    const unsigned int* __restrict__ ebuf, const int* __restrict__ btot,
    int* __restrict__ rowptr, int* __restrict__ col, int n_nodes, int NBU) {
  __shared__ int hist[256];
  __shared__ int lds[256];
  __shared__ int cursor[256];
  __shared__ int ebnd[2];
  const int j = blockIdx.x;
  const int t = threadIdx.x;
  {
    const int a = (2 * t < NBU) ? btot[2 * t] : 0;
    const int b = (2 * t + 1 < NBU) ? btot[2 * t + 1] : 0;
    const int s = a + b;
    lds[t] = s;
    __syncthreads();
#pragma unroll
    for (int off = 1; off < 256; off <<= 1) {
      int p = 0;
      if (t >= off) p = lds[t - off];
      __syncthreads();
      lds[t] += p;
      __syncthreads();
    }
    const int excl = lds[t] - s;
    if (2 * t == j) ebnd[0] = excl;
    if (2 * t + 1 == j) ebnd[0] = excl + a;
    if (2 * t == j + 1) ebnd[1] = excl;
    if (2 * t + 1 == j + 1) ebnd[1] = excl + a;
  }
  __syncthreads();
  const int e0 = ebnd[0], e1 = ebnd[1];
  hist[t] = 0;
  __syncthreads();
  for (int e = e0 + t; e < e1; e += 256)
    atomicAdd(&hist[ebuf[e] >> 17], 1);
  __syncthreads();
  const int h = hist[t];
  lds[t] = h;
  __syncthreads();
#pragma unroll
  for (int off = 1; off < 256; off <<= 1) {
    int p = 0;
    if (t >= off) p = lds[t - off];
    __syncthreads();
    lds[t] += p;
    __syncthreads();
  }
  const int excl = lds[t] - h;
  const int node = (j << 8) + t;
  if (node <= n_nodes) rowptr[node] = e0 + excl;
  cursor[t] = e0 + excl;
  __syncthreads();
  for (int e = e0 + t; e < e1; e += 256) {
    const unsigned int v = ebuf[e];
    const int pos = atomicAdd(&cursor[v >> 17], 1);
    col[pos] = (int)(v & 0x1FFFFu);
  }
}

// ---------------------------------------------------------------------------
// Panel gather: Op[p][n] = Xp[p][n] + sum_j Xp[p][col[j]] for panel pair
// p = 2*(blockIdx&7)+h. Wave = 4 nodes x 2 panels x 8 edge-slots; slot
// reduce via shfl_xor(1/2/4). Per-XCD panel working set 3.2MB -> L2-resident.
// ---------------------------------------------------------------------------
__global__ __launch_bounds__(256) void gather_panel_kernel(
    const unsigned short* __restrict__ Xp, const int* __restrict__ rowptr,
    const int* __restrict__ col, unsigned short* __restrict__ Op,
    int n_nodes) {
  const int q = blockIdx.x & 7;
  const int chunk = blockIdx.x >> 3;
  const int lane = threadIdx.x & 63;
  const int wid = threadIdx.x >> 6;
  const int n2 = lane >> 4;        // 0..3 node within group
  const int h = (lane >> 3) & 1;   // panel within pair
  const int s = lane & 7;          // edge slot
  const unsigned short* Pan = Xp + (size_t)(2 * q + h) * n_nodes * 8;
  unsigned short* OPan = Op + (size_t)(2 * q + h) * n_nodes * 8;
#pragma unroll
  for (int it = 0; it < 4; ++it) {
    const int node = chunk * 64 + wid * 16 + it * 4 + n2;
    const bool valid = node < n_nodes;
    float a0 = 0.f, a1 = 0.f, a2 = 0.f, a3 = 0.f;
    float a4 = 0.f, a5 = 0.f, a6 = 0.f, a7 = 0.f;
    int jbeg = 0, jend = 0;
    if (valid) {
      jbeg = rowptr[node];
      jend = rowptr[node + 1];
      if (s == 0) {  // self term
        const uint4 u = *reinterpret_cast<const uint4*>(Pan + (size_t)node * 8);
        a0 = b2f(u.x << 16); a1 = b2f(u.x & 0xffff0000u);
        a2 = b2f(u.y << 16); a3 = b2f(u.y & 0xffff0000u);
        a4 = b2f(u.z << 16); a5 = b2f(u.z & 0xffff0000u);
        a6 = b2f(u.w << 16); a7 = b2f(u.w & 0xffff0000u);
      }
    }
    int j = jbeg + s;
    for (; j + 8 < jend; j += 16) {
      const int c0 = col[j];
      const int c1 = col[j + 8];
      const uint4 w0 = *reinterpret_cast<const uint4*>(Pan + (size_t)c0 * 8);
      const uint4 w1 = *reinterpret_cast<const uint4*>(Pan + (size_t)c1 * 8);
      a0 += b2f(w0.x << 16); a1 += b2f(w0.x & 0xffff0000u);
      a2 += b2f(w0.y << 16); a3 += b2f(w0.y & 0xffff0000u);
      a4 += b2f(w0.z << 16); a5 += b2f(w0.z & 0xffff0000u);
      a6 += b2f(w0.w << 16); a7 += b2f(w0.w & 0xffff0000u);
      a0 += b2f(w1.x << 16); a1 += b2f(w1.x & 0xffff0000u);
      a2 += b2f(w1.y << 16); a3 += b2f(w1.y & 0xffff0000u);
      a4 += b2f(w1.z << 16); a5 += b2f(w1.z & 0xffff0000u);
      a6 += b2f(w1.w << 16); a7 += b2f(w1.w & 0xffff0000u);
    }
    if (j < jend) {
      const uint4 w = *reinterpret_cast<const uint4*>(Pan + (size_t)col[j] * 8);
      a0 += b2f(w.x << 16); a1 += b2f(w.x & 0xffff0000u);
      a2 += b2f(w.y << 16); a3 += b2f(w.y & 0xffff0000u);
      a4 += b2f(w.z << 16); a5 += b2f(w.z & 0xffff0000u);
      a6 += b2f(w.w << 16); a7 += b2f(w.w & 0xffff0000u);
    }
    // reduce over the 8 edge slots (lane bits 0..2)
    a0 += __shfl_xor(a0, 1, 64); a0 += __shfl_xor(a0, 2, 64); a0 += __shfl_xor(a0, 4, 64);
    a1 += __shfl_xor(a1, 1, 64); a1 += __shfl_xor(a1, 2, 64); a1 += __shfl_xor(a1, 4, 64);
    a2 += __shfl_xor(a2, 1, 64); a2 += __shfl_xor(a2, 2, 64); a2 += __shfl_xor(a2, 4, 64);
    a3 += __shfl_xor(a3, 1, 64); a3 += __shfl_xor(a3, 2, 64); a3 += __shfl_xor(a3, 4, 64);
    a4 += __shfl_xor(a4, 1, 64); a4 += __shfl_xor(a4, 2, 64); a4 += __shfl_xor(a4, 4, 64);
    a5 += __shfl_xor(a5, 1, 64); a5 += __shfl_xor(a5, 2, 64); a5 += __shfl_xor(a5, 4, 64);
    a6 += __shfl_xor(a6, 1, 64); a6 += __shfl_xor(a6, 2, 64); a6 += __shfl_xor(a6, 4, 64);
    a7 += __shfl_xor(a7, 1, 64); a7 += __shfl_xor(a7, 2, 64); a7 += __shfl_xor(a7, 4, 64);
    if (valid && s == 0) {
      uint4 o;
      o.x = pk2(a0, a1);
      o.y = pk2(a2, a3);
      o.z = pk2(a4, a5);
      o.w = pk2(a6, a7);
      *reinterpret_cast<uint4*>(OPan + (size_t)node * 8) = o;
    }
  }
}

// ---------------------------------------------------------------------------
// Fused MLP pair (R13 core, panel IO): out = [relu](relu(S@W1+b1)@W2+b2).
// xf[s] = panel(2s+h) of node strip*32+nl (same values as row-major cols
// s*16+h*8..+8); epilogue stores to the same panel mapping.
// ---------------------------------------------------------------------------
template <int RELU>
__global__ __launch_bounds__(512) void mlp2_kernel(
    const unsigned short* __restrict__ Xp, const unsigned short* __restrict__ Wp1,
    const unsigned short* __restrict__ Wp2, const float* __restrict__ bias1,
    const float* __restrict__ bias2, unsigned short* __restrict__ Op,
    int n_strips, int n_nodes) {
  __shared__ unsigned short wl1[16384];  // 32 KB
  __shared__ unsigned short wl2[16384];  // 32 KB
  __shared__ float bl1[128], bl2[128];

  const int lx = threadIdx.x & 63;
  const int wid = threadIdx.x >> 6;
  const int h = lx >> 5;
  const int nl = lx & 31;
  const int wg = blockIdx.x * 8 + wid;  // global wave id
  const int NW = gridDim.x * 8;
  const int s0 = (int)(((long long)wg * n_strips) / NW);
  const int s1 = (int)(((long long)(wg + 1) * n_strips) / NW);
  const int strip = s0;
  const bool active = (s0 < s1);  // 0 or 1 strips per wave

  bf16x8 xf[8];
  if (active) {
#pragma unroll
    for (int s = 0; s < 8; ++s)
      xf[s] = *reinterpret_cast<const bf16x8*>(
          Xp + ((size_t)(2 * s + h) * n_nodes + strip * 32 + nl) * 8);
  }

  for (int i = threadIdx.x * 8; i < 16384; i += 512 * 8) {
    *reinterpret_cast<bf16x8*>(wl1 + i) = *reinterpret_cast<const bf16x8*>(Wp1 + i);
    *reinterpret_cast<bf16x8*>(wl2 + i) = *reinterpret_cast<const bf16x8*>(Wp2 + i);
  }
  if (threadIdx.x < 128) {
    bl1[threadIdx.x] = bias1[threadIdx.x];
    bl2[threadIdx.x] = bias2[threadIdx.x];
  }
  __syncthreads();
  if (!active) return;

  f32x16 acc1[4];
#pragma unroll
  for (int t1 = 0; t1 < 4; ++t1)
#pragma unroll
    for (int r = 0; r < 16; ++r)
      acc1[t1][r] = bl1[32 * t1 + (r & 3) + 8 * (r >> 2) + 4 * h];
#pragma unroll
  for (int s = 0; s < 8; ++s) {
#pragma unroll
    for (int t1 = 0; t1 < 4; ++t1) {
      const bf16x8 wf = *reinterpret_cast<const bf16x8*>(
          wl1 + ((t1 * 8 + s) * 64 + lx) * 8);
      acc1[t1] =
          __builtin_amdgcn_mfma_f32_32x32x16_bf16(wf, xf[s], acc1[t1], 0, 0, 0);
    }
  }

  f32x16 acc2[4];
#pragma unroll
  for (int t = 0; t < 4; ++t)
#pragma unroll
    for (int r = 0; r < 16; ++r)
      acc2[t][r] = bl2[32 * t + (r & 3) + 8 * (r >> 2) + 4 * h];
#pragma unroll
  for (int s2 = 0; s2 < 8; ++s2) {
    const int t1 = s2 >> 1;
    const int ro = (s2 & 1) << 3;
    const float g0 = fmaxf(acc1[t1][ro + 0], 0.f);
    const float g1 = fmaxf(acc1[t1][ro + 1], 0.f);
    const float g2 = fmaxf(acc1[t1][ro + 2], 0.f);
    const float g3 = fmaxf(acc1[t1][ro + 3], 0.f);
    const float g4 = fmaxf(acc1[t1][ro + 4], 0.f);
    const float g5 = fmaxf(acc1[t1][ro + 5], 0.f);
    const float g6 = fmaxf(acc1[t1][ro + 6], 0.f);
    const float g7 = fmaxf(acc1[t1][ro + 7], 0.f);
    const unsigned int pA0 = pk2(g0, g1), pA1 = pk2(g2, g3);
    const unsigned int pB0 = pk2(g4, g5), pB1 = pk2(g6, g7);
    const unsigned int sA0 = (unsigned int)__shfl((int)pA0, lx ^ 32, 64);
    const unsigned int sA1 = (unsigned int)__shfl((int)pA1, lx ^ 32, 64);
    const unsigned int sB0 = (unsigned int)__shfl((int)pB0, lx ^ 32, 64);
    const unsigned int sB1 = (unsigned int)__shfl((int)pB1, lx ^ 32, 64);
    union { unsigned int u[4]; bf16x8 v; } fr;
    fr.u[0] = h ? sB0 : pA0;
    fr.u[1] = h ? sB1 : pA1;
    fr.u[2] = h ? pB0 : sA0;
    fr.u[3] = h ? pB1 : sA1;
#pragma unroll
    for (int t = 0; t < 4; ++t) {
      const bf16x8 wf = *reinterpret_cast<const bf16x8*>(
          wl2 + ((t * 8 + s2) * 64 + lx) * 8);
      acc2[t] =
          __builtin_amdgcn_mfma_f32_32x32x16_bf16(wf, fr.v, acc2[t], 0, 0, 0);
    }
  }

#pragma unroll
  for (int s = 0; s < 8; ++s) {
    const int t = s >> 1;
    const int ro = (s & 1) << 3;
    float g0 = acc2[t][ro + 0], g1 = acc2[t][ro + 1];
    float g2 = acc2[t][ro + 2], g3 = acc2[t][ro + 3];
    float g4 = acc2[t][ro + 4], g5 = acc2[t][ro + 5];
    float g6 = acc2[t][ro + 6], g7 = acc2[t][ro + 7];
    if (RELU) {
      g0 = fmaxf(g0, 0.f); g1 = fmaxf(g1, 0.f);
      g2 = fmaxf(g2, 0.f); g3 = fmaxf(g3, 0.f);
      g4 = fmaxf(g4, 0.f); g5 = fmaxf(g5, 0.f);
      g6 = fmaxf(g6, 0.f); g7 = fmaxf(g7, 0.f);
    }
    const unsigned int pA0 = pk2(g0, g1), pA1 = pk2(g2, g3);
    const unsigned int pB0 = pk2(g4, g5), pB1 = pk2(g6, g7);
    const unsigned int sA0 = (unsigned int)__shfl((int)pA0, lx ^ 32, 64);
    const unsigned int sA1 = (unsigned int)__shfl((int)pA1, lx ^ 32, 64);
    const unsigned int sB0 = (unsigned int)__shfl((int)pB0, lx ^ 32, 64);
    const unsigned int sB1 = (unsigned int)__shfl((int)pB1, lx ^ 32, 64);
    union { unsigned int u[4]; bf16x8 v; } fr;
    fr.u[0] = h ? sB0 : pA0;
    fr.u[1] = h ? sB1 : pA1;
    fr.u[2] = h ? pB0 : sA0;
    fr.u[3] = h ? pB1 : sA1;
    *reinterpret_cast<bf16x8*>(
        Op + ((size_t)(2 * s + h) * n_nodes + strip * 32 + nl) * 8) = fr.v;
  }
}

// ---------------------------------------------------------------------------
// pool1 (panel layout): block (g, q): panels q*4..q*4+3; binary search for
// graph range; direct mean write.
// ---------------------------------------------------------------------------
__global__ __launch_bounds__(256) void pool1_kernel(
    const unsigned short* __restrict__ Hp, const int* __restrict__ batch,
    float* __restrict__ out, int n_nodes) {
  __shared__ float red[256][8];
  __shared__ int bnd[2];
  const int g = blockIdx.x >> 2;
  const int q = blockIdx.x & 3;
  const int t = threadIdx.x;
  if (t == 0) {
    bnd[0] = lbound(batch, n_nodes, g);
    bnd[1] = lbound(batch, n_nodes, g + 1);
  }
  __syncthreads();
  const int start = bnd[0], end = bnd[1];
  const int pp = q * 4 + (t & 3);
  const unsigned short* Pan = Hp + (size_t)pp * n_nodes * 8;
  float a[8] = {0.f, 0.f, 0.f, 0.f, 0.f, 0.f, 0.f, 0.f};
  for (int r = start + (t >> 2); r < end; r += 64) {
    const uint4 v = *reinterpret_cast<const uint4*>(Pan + (size_t)r * 8);
    a[0] += b2f(v.x << 16); a[1] += b2f(v.x & 0xffff0000u);
    a[2] += b2f(v.y << 16); a[3] += b2f(v.y & 0xffff0000u);
    a[4] += b2f(v.z << 16); a[5] += b2f(v.z & 0xffff0000u);
    a[6] += b2f(v.w << 16); a[7] += b2f(v.w & 0xffff0000u);
  }
#pragma unroll
  for (int k = 0; k < 8; ++k) red[t][k] = a[k];
  __syncthreads();
#pragma unroll
  for (int off = 128; off >= 4; off >>= 1) {
    if (t < off) {
#pragma unroll
      for (int k = 0; k < 8; ++k) red[t][k] += red[t + off][k];
    }
    __syncthreads();
  }
  if (t < 4) {
    const float inv = 1.0f / (float)max(end - start, 1);
    const int ppp = q * 4 + t;
#pragma unroll
    for (int k = 0; k < 8; ++k)
      out[(size_t)g * D + ppp * 8 + k] = red[t][k] * inv;
  }
}

// ---------------------------------------------------------------------------
extern "C" void kernel_launch(void* const* d_in, const int* in_sizes, int n_in,
                              void* d_out, int out_size, void* d_ws,
                              size_t ws_size, hipStream_t stream) {
  const float* x = (const float*)d_in[0];
  const int* ei = (const int*)d_in[1];
  const int* batch = (const int*)d_in[2];
  const float* B[6] = {(const float*)d_in[4],  (const float*)d_in[6],
                       (const float*)d_in[8],  (const float*)d_in[10],
                       (const float*)d_in[12], (const float*)d_in[14]};

  const int n_nodes = in_sizes[2];
  const int n_edges = in_sizes[1] / 2;
  const int n_graphs = out_size / D;
  const int* src = ei;
  const int* dst = ei + n_edges;

  const size_t matB = (size_t)n_nodes * D * sizeof(unsigned short);  // 25.6 MB
  unsigned short* bufA = (unsigned short*)d_ws;
  unsigned short* bufB = (unsigned short*)((char*)d_ws + matB);
  unsigned short* bufC = (unsigned short*)((char*)d_ws + 2 * matB);
  unsigned short* wpack = (unsigned short*)((char*)d_ws + 3 * matB);
  int* rowptr = (int*)((char*)wpack + 6 * 16384 * sizeof(unsigned short));
  int* colidx = rowptr + (n_nodes + 1);
  unsigned int* ebuf = (unsigned int*)(colidx + n_edges);
  const int NBU = (n_nodes + 255) >> 8;  // 391
  int* bcount = (int*)(ebuf + n_edges);
  int* boff = bcount + (size_t)NB_E * NBU;
  int* btot = boff + (size_t)NB_E * NBU;

  const dim3 blk(256);
  const int n_strips = n_nodes / 32;  // 100000 % 32 == 0
  const int mlp_grid = 512;           // Bresenham strip assignment
  const int epb = (n_edges + NB_E - 1) / NB_E;
  const int conv_blocks = (n_nodes + 127) / 128;
  const int prep_blocks = NB_E + 48 + conv_blocks;
  const int gather_blocks = 8 * ((n_nodes + 63) / 64);

  // ---- prep (bktA + pack + panel convert) + counting-sort CSR ----
  prep_kernel<<<prep_blocks, blk, 0, stream>>>(
      x, bufA, (const float*)d_in[3], (const float*)d_in[5],
      (const float*)d_in[7], (const float*)d_in[9], (const float*)d_in[11],
      (const float*)d_in[13], wpack, dst, bcount, n_nodes, n_edges, NBU, epb);
  bktB_kernel<<<NBU, blk, 0, stream>>>(bcount, boff, btot, NBU);
  bktC_kernel<<<NB_E, blk, 0, stream>>>(src, dst, boff, btot, ebuf, n_edges,
                                        NBU, epb);
  bktD_kernel<<<NBU, blk, 0, stream>>>(ebuf, btot, rowptr, colidx, n_nodes,
                                       NBU);

  // ---- layer 1 ----
  gather_panel_kernel<<<gather_blocks, blk, 0, stream>>>(bufA, rowptr, colidx,
                                                         bufB, n_nodes);
  mlp2_kernel<1><<<mlp_grid, 512, 0, stream>>>(bufB, wpack + 0 * 16384,
                                               wpack + 1 * 16384, B[0], B[1],
                                               bufC, n_strips, n_nodes);
  // ---- layer 2 ----
  gather_panel_kernel<<<gather_blocks, blk, 0, stream>>>(bufC, rowptr, colidx,
                                                         bufB, n_nodes);
  mlp2_kernel<1><<<mlp_grid, 512, 0, stream>>>(bufB, wpack + 2 * 16384,
                                               wpack + 3 * 16384, B[2], B[3],
                                               bufA, n_strips, n_nodes);
  // ---- layer 3 ----
  gather_panel_kernel<<<gather_blocks, blk, 0, stream>>>(bufA, rowptr, colidx,
                                                         bufB, n_nodes);
  mlp2_kernel<0><<<mlp_grid, 512, 0, stream>>>(bufB, wpack + 4 * 16384,
                                               wpack + 5 * 16384, B[4], B[5],
                                               bufC, n_strips, n_nodes);

  // ---- global mean pool ----
  pool1_kernel<<<n_graphs * 4, blk, 0, stream>>>(bufC, batch, (float*)d_out,
                                                 n_nodes);
}

// Round 16
// 310.572 us; speedup vs baseline: 1.5728x; 1.5728x over previous
//
#include <hip/hip_runtime.h>

#define D 128
#define NB_E 512  // edge-slice blocks for bucket count/scatter

typedef __attribute__((ext_vector_type(8))) short bf16x8;
typedef __attribute__((ext_vector_type(16))) float f32x16;

__device__ inline float b2f(unsigned int hi16_as_lo) {
  union { unsigned int u; float f; } v;
  v.u = hi16_as_lo;
  return v.f;
}
__device__ inline unsigned short f2b(float f) {  // RNE f32 -> bf16
  union { float f; unsigned int u; } v;
  v.f = f;
  unsigned int r = v.u + 0x7FFFu + ((v.u >> 16) & 1u);
  return (unsigned short)(r >> 16);
}
__device__ inline unsigned int pk2(float lo, float hi) {
  return (unsigned int)f2b(lo) | ((unsigned int)f2b(hi) << 16);
}
__device__ inline int lbound(const int* __restrict__ a, int n, int key) {
  int lo = 0, hi = n;
  while (lo < hi) {
    int mid = (lo + hi) >> 1;
    if (a[mid] < key) lo = mid + 1; else hi = mid;
  }
  return lo;
}

// ---------------------------------------------------------------------------
// prep: fused {bktA histogram | weight pack x6 | f32->bf16 convert}
// blocks [0,NB_E): bktA; [NB_E,NB_E+48): pack; rest: convert.
// ---------------------------------------------------------------------------
__global__ __launch_bounds__(256) void prep_kernel(
    const float* __restrict__ x, unsigned short* __restrict__ xb,
    const float* __restrict__ w0, const float* __restrict__ w1,
    const float* __restrict__ w2, const float* __restrict__ w3,
    const float* __restrict__ w4, const float* __restrict__ w5,
    unsigned short* __restrict__ Wp, const int* __restrict__ dst,
    int* __restrict__ bcount, int n8, int n_edges, int NBU, int epb) {
  __shared__ int cnt[512];
  const int b = blockIdx.x;
  if (b < NB_E) {  // ---- bktA ----
    for (int i = threadIdx.x; i < NBU; i += 256) cnt[i] = 0;
    __syncthreads();
    const int e0 = b * epb;
    const int e1 = min(e0 + epb, n_edges);
    for (int e = e0 + threadIdx.x; e < e1; e += 256)
      atomicAdd(&cnt[dst[e] >> 8], 1);
    __syncthreads();
    int* out = bcount + (size_t)b * NBU;
    for (int i = threadIdx.x; i < NBU; i += 256) out[i] = cnt[i];
  } else if (b < NB_E + 48) {  // ---- pack ----
    const int bb = b - NB_E;
    const int m = bb >> 3;
    const float* W = m == 0 ? w0
                   : m == 1 ? w1
                   : m == 2 ? w2
                   : m == 3 ? w3
                   : m == 4 ? w4
                            : w5;
    const int idx = (bb & 7) * 256 + threadIdx.x;  // 0..2047
    const int l = idx & 63;
    const int s = (idx >> 6) & 7;
    const int t = idx >> 9;
    const int n = (t << 5) + (l & 31);
    const int k0 = (s << 4) + ((l >> 5) << 3);
    unsigned short o[8];
#pragma unroll
    for (int i = 0; i < 8; ++i) o[i] = f2b(W[(size_t)(k0 + i) * D + n]);
    *reinterpret_cast<bf16x8*>(Wp + (size_t)m * 16384 + (size_t)idx * 8) =
        *reinterpret_cast<bf16x8*>(o);
  } else {  // ---- convert ----
    const int i = (b - NB_E - 48) * 256 + threadIdx.x;
    if (i < n8) {
      const float4 a = *reinterpret_cast<const float4*>(x + (size_t)i * 8);
      const float4 c = *reinterpret_cast<const float4*>(x + (size_t)i * 8 + 4);
      unsigned short o[8] = {f2b(a.x), f2b(a.y), f2b(a.z), f2b(a.w),
                             f2b(c.x), f2b(c.y), f2b(c.z), f2b(c.w)};
      *reinterpret_cast<bf16x8*>(xb + (size_t)i * 8) =
          *reinterpret_cast<bf16x8*>(o);
    }
  }
}

// ---------------------------------------------------------------------------
// bktB: per bucket j, exclusive scan of bcount[b][j] over blocks b.
// ---------------------------------------------------------------------------
__global__ __launch_bounds__(256) void bktB_kernel(
    const int* __restrict__ bcount, int* __restrict__ boff,
    int* __restrict__ btot, int NBU) {
  __shared__ int lds[256];
  const int j = blockIdx.x;
  const int t = threadIdx.x;
  const int a = bcount[(size_t)(2 * t) * NBU + j];
  const int b = bcount[(size_t)(2 * t + 1) * NBU + j];
  const int s = a + b;
  lds[t] = s;
  __syncthreads();
#pragma unroll
  for (int off = 1; off < 256; off <<= 1) {
    int p = 0;
    if (t >= off) p = lds[t - off];
    __syncthreads();
    lds[t] += p;
    __syncthreads();
  }
  const int excl = lds[t] - s;
  boff[(size_t)(2 * t) * NBU + j] = excl;
  boff[(size_t)(2 * t + 1) * NBU + j] = excl + a;
  if (t == 255) btot[j] = lds[255];
}

// ---------------------------------------------------------------------------
// bktC: scatter edges into bucket-grouped ebuf ((dstLocal<<17)|src).
// base[] derived locally from btot via LDS scan.
// ---------------------------------------------------------------------------
__global__ __launch_bounds__(256) void bktC_kernel(
    const int* __restrict__ src, const int* __restrict__ dst,
    const int* __restrict__ boff, const int* __restrict__ btot,
    unsigned int* __restrict__ ebuf, int n_edges, int NBU, int epb) {
  __shared__ int cur[512];
  __shared__ int scan[256];
  const int t = threadIdx.x;
  const int a = (2 * t < NBU) ? btot[2 * t] : 0;
  const int b = (2 * t + 1 < NBU) ? btot[2 * t + 1] : 0;
  const int s = a + b;
  scan[t] = s;
  __syncthreads();
#pragma unroll
  for (int off = 1; off < 256; off <<= 1) {
    int p = 0;
    if (t >= off) p = scan[t - off];
    __syncthreads();
    scan[t] += p;
    __syncthreads();
  }
  const int excl = scan[t] - s;
  const int* bo = boff + (size_t)blockIdx.x * NBU;
  if (2 * t < NBU) cur[2 * t] = excl + bo[2 * t];
  if (2 * t + 1 < NBU) cur[2 * t + 1] = excl + a + bo[2 * t + 1];
  __syncthreads();
  const int e0 = blockIdx.x * epb;
  const int e1 = min(e0 + epb, n_edges);
  for (int e = e0 + t; e < e1; e += 256) {
    const int d = dst[e];
    const int pos = atomicAdd(&cur[d >> 8], 1);
    ebuf[pos] = ((unsigned int)(d & 255) << 17) | (unsigned int)src[e];
  }
}

// ---------------------------------------------------------------------------
// bktD: per bucket, LDS hist -> scan -> rowptr + LDS-cursor fill of col.
// ---------------------------------------------------------------------------
__global__ __launch_bounds__(256) void bktD_kernel(
    const unsigned int* __restrict__ ebuf, const int* __restrict__ btot,
    int* __restrict__ rowptr, int* __restrict__ col, int n_nodes, int NBU) {
  __shared__ int hist[256];
  __shared__ int lds[256];
  __shared__ int cursor[256];
  __shared__ int ebnd[2];
  const int j = blockIdx.x;
  const int t = threadIdx.x;
  {
    const int a = (2 * t < NBU) ? btot[2 * t] : 0;
    const int b = (2 * t + 1 < NBU) ? btot[2 * t + 1] : 0;
    const int s = a + b;
    lds[t] = s;
    __syncthreads();
#pragma unroll
    for (int off = 1; off < 256; off <<= 1) {
      int p = 0;
      if (t >= off) p = lds[t - off];
      __syncthreads();
      lds[t] += p;
      __syncthreads();
    }
    const int excl = lds[t] - s;
    if (2 * t == j) ebnd[0] = excl;
    if (2 * t + 1 == j) ebnd[0] = excl + a;
    if (2 * t == j + 1) ebnd[1] = excl;
    if (2 * t + 1 == j + 1) ebnd[1] = excl + a;
  }
  __syncthreads();
  const int e0 = ebnd[0], e1 = ebnd[1];
  hist[t] = 0;
  __syncthreads();
  for (int e = e0 + t; e < e1; e += 256)
    atomicAdd(&hist[ebuf[e] >> 17], 1);
  __syncthreads();
  const int h = hist[t];
  lds[t] = h;
  __syncthreads();
#pragma unroll
  for (int off = 1; off < 256; off <<= 1) {
    int p = 0;
    if (t >= off) p = lds[t - off];
    __syncthreads();
    lds[t] += p;
    __syncthreads();
  }
  const int excl = lds[t] - h;
  const int node = (j << 8) + t;
  if (node <= n_nodes) rowptr[node] = e0 + excl;
  cursor[t] = e0 + excl;
  __syncthreads();
  for (int e = e0 + t; e < e1; e += 256) {
    const unsigned int v = ebuf[e];
    const int pos = atomicAdd(&cursor[v >> 17], 1);
    col[pos] = (int)(v & 0x1FFFFu);
  }
}

// ---------------------------------------------------------------------------
// Gather aggregation (bf16): out[n] = X[n] + sum_{j} X[col[j]]
// 32 lanes/node: 16 feature-lanes (uint4) x 2 edge-slots; shfl_xor(16) reduce.
// Structural floor ~60us: random 256B-row gather from a 25.6MB table —
// coalesced+L3-served (R14) beats L2-resident-but-scattered (R15, 129us).
// ---------------------------------------------------------------------------
__global__ __launch_bounds__(256) void gather_bf16_kernel(
    const unsigned short* __restrict__ X, const int* __restrict__ rowptr,
    const int* __restrict__ col, unsigned short* __restrict__ out,
    int n_nodes) {
  const int t = blockIdx.x * 256 + threadIdx.x;
  const int g = t >> 5;
  if (g >= n_nodes) return;
  const int c = t & 15;           // 16B feature chunk
  const int slot = (t >> 4) & 1;  // edge parity
  const uint4* Xv = reinterpret_cast<const uint4*>(X);
  float a0 = 0.f, a1 = 0.f, a2 = 0.f, a3 = 0.f;
  float a4 = 0.f, a5 = 0.f, a6 = 0.f, a7 = 0.f;
  if (slot == 0) {  // self term
    const uint4 u = Xv[(size_t)g * 16 + c];
    a0 = b2f(u.x << 16); a1 = b2f(u.x & 0xffff0000u);
    a2 = b2f(u.y << 16); a3 = b2f(u.y & 0xffff0000u);
    a4 = b2f(u.z << 16); a5 = b2f(u.z & 0xffff0000u);
    a6 = b2f(u.w << 16); a7 = b2f(u.w & 0xffff0000u);
  }
  const int beg = rowptr[g], end = rowptr[g + 1];
  int j = beg + slot;
  for (; j + 6 < end; j += 8) {  // 4 edges per slot-iteration
    const int s0 = col[j + 0];
    const int s1 = col[j + 2];
    const int s2 = col[j + 4];
    const int s3 = col[j + 6];
    const uint4 w0 = Xv[(size_t)s0 * 16 + c];
    const uint4 w1 = Xv[(size_t)s1 * 16 + c];
    const uint4 w2 = Xv[(size_t)s2 * 16 + c];
    const uint4 w3 = Xv[(size_t)s3 * 16 + c];
    a0 += b2f(w0.x << 16); a1 += b2f(w0.x & 0xffff0000u);
    a2 += b2f(w0.y << 16); a3 += b2f(w0.y & 0xffff0000u);
    a4 += b2f(w0.z << 16); a5 += b2f(w0.z & 0xffff0000u);
    a6 += b2f(w0.w << 16); a7 += b2f(w0.w & 0xffff0000u);
    a0 += b2f(w1.x << 16); a1 += b2f(w1.x & 0xffff0000u);
    a2 += b2f(w1.y << 16); a3 += b2f(w1.y & 0xffff0000u);
    a4 += b2f(w1.z << 16); a5 += b2f(w1.z & 0xffff0000u);
    a6 += b2f(w1.w << 16); a7 += b2f(w1.w & 0xffff0000u);
    a0 += b2f(w2.x << 16); a1 += b2f(w2.x & 0xffff0000u);
    a2 += b2f(w2.y << 16); a3 += b2f(w2.y & 0xffff0000u);
    a4 += b2f(w2.z << 16); a5 += b2f(w2.z & 0xffff0000u);
    a6 += b2f(w2.w << 16); a7 += b2f(w2.w & 0xffff0000u);
    a0 += b2f(w3.x << 16); a1 += b2f(w3.x & 0xffff0000u);
    a2 += b2f(w3.y << 16); a3 += b2f(w3.y & 0xffff0000u);
    a4 += b2f(w3.z << 16); a5 += b2f(w3.z & 0xffff0000u);
    a6 += b2f(w3.w << 16); a7 += b2f(w3.w & 0xffff0000u);
  }
  for (; j < end; j += 2) {
    const uint4 w = Xv[(size_t)col[j] * 16 + c];
    a0 += b2f(w.x << 16); a1 += b2f(w.x & 0xffff0000u);
    a2 += b2f(w.y << 16); a3 += b2f(w.y & 0xffff0000u);
    a4 += b2f(w.z << 16); a5 += b2f(w.z & 0xffff0000u);
    a6 += b2f(w.w << 16); a7 += b2f(w.w & 0xffff0000u);
  }
  a0 += __shfl_xor(a0, 16, 64);
  a1 += __shfl_xor(a1, 16, 64);
  a2 += __shfl_xor(a2, 16, 64);
  a3 += __shfl_xor(a3, 16, 64);
  a4 += __shfl_xor(a4, 16, 64);
  a5 += __shfl_xor(a5, 16, 64);
  a6 += __shfl_xor(a6, 16, 64);
  a7 += __shfl_xor(a7, 16, 64);
  if (slot == 0) {
    uint4 o;
    o.x = pk2(a0, a1);
    o.y = pk2(a2, a3);
    o.z = pk2(a4, a5);
    o.w = pk2(a6, a7);
    reinterpret_cast<uint4*>(out)[(size_t)g * 16 + c] = o;
  }
}

// ---------------------------------------------------------------------------
// Fused MLP pair: out = [relu](relu(S@W1+b1)@W2+b2), bf16 io, f32 acc.
// Grid 512 (2 blocks/CU), Bresenham strip assignment (0 or 1 strips/wave).
// ---------------------------------------------------------------------------
template <int RELU>
__global__ __launch_bounds__(512) void mlp2_kernel(
    const unsigned short* __restrict__ X, const unsigned short* __restrict__ Wp1,
    const unsigned short* __restrict__ Wp2, const float* __restrict__ bias1,
    const float* __restrict__ bias2, unsigned short* __restrict__ out,
    int n_strips) {
  __shared__ unsigned short wl1[16384];  // 32 KB
  __shared__ unsigned short wl2[16384];  // 32 KB
  __shared__ float bl1[128], bl2[128];

  const int lx = threadIdx.x & 63;
  const int wid = threadIdx.x >> 6;
  const int h = lx >> 5;
  const int nl = lx & 31;
  const int wg = blockIdx.x * 8 + wid;  // global wave id
  const int NW = gridDim.x * 8;
  const int s0 = (int)(((long long)wg * n_strips) / NW);
  const int s1 = (int)(((long long)(wg + 1) * n_strips) / NW);
  const int strip = s0;
  const bool active = (s0 < s1);  // 0 or 1 strips per wave

  bf16x8 xf[8];
  if (active) {
    const unsigned short* xrow = X + (size_t)(strip * 32 + nl) * D + h * 8;
#pragma unroll
    for (int s = 0; s < 8; ++s)
      xf[s] = *reinterpret_cast<const bf16x8*>(xrow + s * 16);
  }

  for (int i = threadIdx.x * 8; i < 16384; i += 512 * 8) {
    *reinterpret_cast<bf16x8*>(wl1 + i) = *reinterpret_cast<const bf16x8*>(Wp1 + i);
    *reinterpret_cast<bf16x8*>(wl2 + i) = *reinterpret_cast<const bf16x8*>(Wp2 + i);
  }
  if (threadIdx.x < 128) {
    bl1[threadIdx.x] = bias1[threadIdx.x];
    bl2[threadIdx.x] = bias2[threadIdx.x];
  }
  __syncthreads();
  if (!active) return;

  f32x16 acc1[4];
#pragma unroll
  for (int t1 = 0; t1 < 4; ++t1)
#pragma unroll
    for (int r = 0; r < 16; ++r)
      acc1[t1][r] = bl1[32 * t1 + (r & 3) + 8 * (r >> 2) + 4 * h];
#pragma unroll
  for (int s = 0; s < 8; ++s) {
#pragma unroll
    for (int t1 = 0; t1 < 4; ++t1) {
      const bf16x8 wf = *reinterpret_cast<const bf16x8*>(
          wl1 + ((t1 * 8 + s) * 64 + lx) * 8);
      acc1[t1] =
          __builtin_amdgcn_mfma_f32_32x32x16_bf16(wf, xf[s], acc1[t1], 0, 0, 0);
    }
  }

  f32x16 acc2[4];
#pragma unroll
  for (int t = 0; t < 4; ++t)
#pragma unroll
    for (int r = 0; r < 16; ++r)
      acc2[t][r] = bl2[32 * t + (r & 3) + 8 * (r >> 2) + 4 * h];
#pragma unroll
  for (int s2 = 0; s2 < 8; ++s2) {
    const int t1 = s2 >> 1;
    const int ro = (s2 & 1) << 3;
    const float g0 = fmaxf(acc1[t1][ro + 0], 0.f);
    const float g1 = fmaxf(acc1[t1][ro + 1], 0.f);
    const float g2 = fmaxf(acc1[t1][ro + 2], 0.f);
    const float g3 = fmaxf(acc1[t1][ro + 3], 0.f);
    const float g4 = fmaxf(acc1[t1][ro + 4], 0.f);
    const float g5 = fmaxf(acc1[t1][ro + 5], 0.f);
    const float g6 = fmaxf(acc1[t1][ro + 6], 0.f);
    const float g7 = fmaxf(acc1[t1][ro + 7], 0.f);
    const unsigned int pA0 = pk2(g0, g1), pA1 = pk2(g2, g3);
    const unsigned int pB0 = pk2(g4, g5), pB1 = pk2(g6, g7);
    const unsigned int sA0 = (unsigned int)__shfl((int)pA0, lx ^ 32, 64);
    const unsigned int sA1 = (unsigned int)__shfl((int)pA1, lx ^ 32, 64);
    const unsigned int sB0 = (unsigned int)__shfl((int)pB0, lx ^ 32, 64);
    const unsigned int sB1 = (unsigned int)__shfl((int)pB1, lx ^ 32, 64);
    union { unsigned int u[4]; bf16x8 v; } fr;
    fr.u[0] = h ? sB0 : pA0;
    fr.u[1] = h ? sB1 : pA1;
    fr.u[2] = h ? pB0 : sA0;
    fr.u[3] = h ? pB1 : sA1;
#pragma unroll
    for (int t = 0; t < 4; ++t) {
      const bf16x8 wf = *reinterpret_cast<const bf16x8*>(
          wl2 + ((t * 8 + s2) * 64 + lx) * 8);
      acc2[t] =
          __builtin_amdgcn_mfma_f32_32x32x16_bf16(wf, fr.v, acc2[t], 0, 0, 0);
    }
  }

  unsigned short* orow = out + (size_t)(strip * 32 + nl) * D + h * 8;
#pragma unroll
  for (int s = 0; s < 8; ++s) {
    const int t = s >> 1;
    const int ro = (s & 1) << 3;
    float g0 = acc2[t][ro + 0], g1 = acc2[t][ro + 1];
    float g2 = acc2[t][ro + 2], g3 = acc2[t][ro + 3];
    float g4 = acc2[t][ro + 4], g5 = acc2[t][ro + 5];
    float g6 = acc2[t][ro + 6], g7 = acc2[t][ro + 7];
    if (RELU) {
      g0 = fmaxf(g0, 0.f); g1 = fmaxf(g1, 0.f);
      g2 = fmaxf(g2, 0.f); g3 = fmaxf(g3, 0.f);
      g4 = fmaxf(g4, 0.f); g5 = fmaxf(g5, 0.f);
      g6 = fmaxf(g6, 0.f); g7 = fmaxf(g7, 0.f);
    }
    const unsigned int pA0 = pk2(g0, g1), pA1 = pk2(g2, g3);
    const unsigned int pB0 = pk2(g4, g5), pB1 = pk2(g6, g7);
    const unsigned int sA0 = (unsigned int)__shfl((int)pA0, lx ^ 32, 64);
    const unsigned int sA1 = (unsigned int)__shfl((int)pA1, lx ^ 32, 64);
    const unsigned int sB0 = (unsigned int)__shfl((int)pB0, lx ^ 32, 64);
    const unsigned int sB1 = (unsigned int)__shfl((int)pB1, lx ^ 32, 64);
    union { unsigned int u[4]; bf16x8 v; } fr;
    fr.u[0] = h ? sB0 : pA0;
    fr.u[1] = h ? sB1 : pA1;
    fr.u[2] = h ? pB0 : sA0;
    fr.u[3] = h ? pB1 : sA1;
    *reinterpret_cast<bf16x8*>(orow + s * 16) = fr.v;
  }
}

// ---------------------------------------------------------------------------
// pool1: one block per (graph, col-quarter). Graph range via binary search
// on sorted batch; direct mean write (no atomics, no memsets, no norm pass).
// ---------------------------------------------------------------------------
__global__ __launch_bounds__(256) void pool1_kernel(
    const unsigned short* __restrict__ H, const int* __restrict__ batch,
    float* __restrict__ out, int n_nodes) {
  __shared__ float red[256][4];
  __shared__ int bnd[2];
  const int g = blockIdx.x >> 2;
  const int q = blockIdx.x & 3;
  const int t = threadIdx.x;
  if (t == 0) {
    bnd[0] = lbound(batch, n_nodes, g);
    bnd[1] = lbound(batch, n_nodes, g + 1);
  }
  __syncthreads();
  const int start = bnd[0], end = bnd[1];
  const int c = q * 8 + (t & 7);  // uint2 chunk (4 bf16)
  const uint2* Hv = reinterpret_cast<const uint2*>(H);
  float a0 = 0.f, a1 = 0.f, a2 = 0.f, a3 = 0.f;
  for (int r = start + (t >> 3); r < end; r += 32) {
    const uint2 v = Hv[(size_t)r * 32 + c];
    a0 += b2f(v.x << 16);
    a1 += b2f(v.x & 0xffff0000u);
    a2 += b2f(v.y << 16);
    a3 += b2f(v.y & 0xffff0000u);
  }
  red[t][0] = a0;
  red[t][1] = a1;
  red[t][2] = a2;
  red[t][3] = a3;
  __syncthreads();
#pragma unroll
  for (int off = 16; off >= 1; off >>= 1) {
    if ((t >> 3) < off) {
#pragma unroll
      for (int k = 0; k < 4; ++k) red[t][k] += red[t + off * 8][k];
    }
    __syncthreads();
  }
  if (t < 8) {
    const float inv = 1.0f / (float)max(end - start, 1);
    const int cc = q * 8 + t;
#pragma unroll
    for (int k = 0; k < 4; ++k)
      out[(size_t)g * D + cc * 4 + k] = red[t][k] * inv;
  }
}

// ---------------------------------------------------------------------------
extern "C" void kernel_launch(void* const* d_in, const int* in_sizes, int n_in,
                              void* d_out, int out_size, void* d_ws,
                              size_t ws_size, hipStream_t stream) {
  const float* x = (const float*)d_in[0];
  const int* ei = (const int*)d_in[1];
  const int* batch = (const int*)d_in[2];
  const float* B[6] = {(const float*)d_in[4],  (const float*)d_in[6],
                       (const float*)d_in[8],  (const float*)d_in[10],
                       (const float*)d_in[12], (const float*)d_in[14]};

  const int n_nodes = in_sizes[2];
  const int n_edges = in_sizes[1] / 2;
  const int n_graphs = out_size / D;
  const int* src = ei;
  const int* dst = ei + n_edges;

  const size_t matB = (size_t)n_nodes * D * sizeof(unsigned short);  // 25.6 MB
  unsigned short* bufA = (unsigned short*)d_ws;
  unsigned short* bufB = (unsigned short*)((char*)d_ws + matB);
  unsigned short* bufC = (unsigned short*)((char*)d_ws + 2 * matB);
  unsigned short* wpack = (unsigned short*)((char*)d_ws + 3 * matB);
  int* rowptr = (int*)((char*)wpack + 6 * 16384 * sizeof(unsigned short));
  int* colidx = rowptr + (n_nodes + 1);
  unsigned int* ebuf = (unsigned int*)(colidx + n_edges);
  const int NBU = (n_nodes + 255) >> 8;  // 391
  int* bcount = (int*)(ebuf + n_edges);
  int* boff = bcount + (size_t)NB_E * NBU;
  int* btot = boff + (size_t)NB_E * NBU;

  const dim3 blk(256);
  const int gather_blocks = (int)(((long long)n_nodes * 32 + 255) / 256);
  const int n_strips = n_nodes / 32;  // 100000 % 32 == 0
  const int mlp_grid = 512;           // Bresenham strip assignment
  const int epb = (n_edges + NB_E - 1) / NB_E;
  const int n8 = n_nodes * (D / 8);
  const int prep_blocks = NB_E + 48 + (n8 + 255) / 256;

  // ---- prep (convert + pack + bktA) + counting-sort CSR ----
  prep_kernel<<<prep_blocks, blk, 0, stream>>>(
      x, bufA, (const float*)d_in[3], (const float*)d_in[5],
      (const float*)d_in[7], (const float*)d_in[9], (const float*)d_in[11],
      (const float*)d_in[13], wpack, dst, bcount, n8, n_edges, NBU, epb);
  bktB_kernel<<<NBU, blk, 0, stream>>>(bcount, boff, btot, NBU);
  bktC_kernel<<<NB_E, blk, 0, stream>>>(src, dst, boff, btot, ebuf, n_edges,
                                        NBU, epb);
  bktD_kernel<<<NBU, blk, 0, stream>>>(ebuf, btot, rowptr, colidx, n_nodes,
                                       NBU);

  // ---- layer 1 ----
  gather_bf16_kernel<<<gather_blocks, blk, 0, stream>>>(bufA, rowptr, colidx,
                                                        bufB, n_nodes);
  mlp2_kernel<1><<<mlp_grid, 512, 0, stream>>>(bufB, wpack + 0 * 16384,
                                               wpack + 1 * 16384, B[0], B[1],
                                               bufC, n_strips);
  // ---- layer 2 ----
  gather_bf16_kernel<<<gather_blocks, blk, 0, stream>>>(bufC, rowptr, colidx,
                                                        bufB, n_nodes);
  mlp2_kernel<1><<<mlp_grid, 512, 0, stream>>>(bufB, wpack + 2 * 16384,
                                               wpack + 3 * 16384, B[2], B[3],
                                               bufA, n_strips);
  // ---- layer 3 ----
  gather_bf16_kernel<<<gather_blocks, blk, 0, stream>>>(bufA, rowptr, colidx,
                                                        bufB, n_nodes);
  mlp2_kernel<0><<<mlp_grid, 512, 0, stream>>>(bufB, wpack + 4 * 16384,
                                               wpack + 5 * 16384, B[4], B[5],
                                               bufC, n_strips);

  // ---- global mean pool (single kernel) ----
  pool1_kernel<<<n_graphs * 4, blk, 0, stream>>>(bufC, batch, (float*)d_out,
                                                 n_nodes);
}